// Round 1
// baseline (240.536 us; speedup 1.0000x reference)
//
#include <hip/hip_runtime.h>

#define SORT_MAX 8192  // max n2 for single-block bitonic (64 KB LDS)

// ---------------------------------------------------------------------------
// Kernel 1: per-Gaussian preprocessing.
// Computes projection, 2D covariance inverse, radius (areas output), color
// from SH, opacity, conservative cull radius^2, and the depth sort key.
// ---------------------------------------------------------------------------
__global__ __launch_bounds__(256) void k_pre(
    const float* __restrict__ pws, const float* __restrict__ shs,
    const float* __restrict__ alphas_raw, const float* __restrict__ scales_raw,
    const float* __restrict__ rots_raw, const float* __restrict__ Rcw,
    const float* __restrict__ tcw, const float* __restrict__ intr,
    int N, int W, int H, float* __restrict__ areas,
    unsigned long long* __restrict__ keys, float* __restrict__ P)
{
    int i = blockIdx.x * 256 + threadIdx.x;
    if (i >= N) return;

    float R00=Rcw[0],R01=Rcw[1],R02=Rcw[2];
    float R10=Rcw[3],R11=Rcw[4],R12=Rcw[5];
    float R20=Rcw[6],R21=Rcw[7],R22=Rcw[8];
    float t0=tcw[0],t1=tcw[1],t2=tcw[2];
    float fx=intr[0],fy=intr[1],cx=intr[2],cy=intr[3];

    float pwx=pws[i*3+0], pwy=pws[i*3+1], pwz=pws[i*3+2];
    float pcx = R00*pwx + R01*pwy + R02*pwz + t0;
    float pcy = R10*pwx + R11*pwy + R12*pwz + t1;
    float pcz = R20*pwx + R21*pwy + R22*pwz + t2;
    float depth = pcz;
    float zs = (depth > 0.2f) ? depth : 1.0f;
    float u0 = fx * pcx / zs + cx;
    float u1 = fy * pcy / zs + cy;

    // quaternion -> rotation
    float qw=rots_raw[i*4+0], qx=rots_raw[i*4+1], qy=rots_raw[i*4+2], qz=rots_raw[i*4+3];
    float qn = sqrtf(qw*qw + qx*qx + qy*qy + qz*qz);
    qw/=qn; qx/=qn; qy/=qn; qz/=qn;
    float s0 = expf(scales_raw[i*3+0]);
    float s1 = expf(scales_raw[i*3+1]);
    float s2 = expf(scales_raw[i*3+2]);

    float xx=qx*qx, yy=qy*qy, zq=qz*qz;
    float xy=qx*qy, xz=qx*qz, yz=qy*qz;
    float wx=qw*qx, wy=qw*qy, wz=qw*qz;
    float r00=1.f-2.f*(yy+zq), r01=2.f*(xy-wz),     r02=2.f*(xz+wy);
    float r10=2.f*(xy+wz),     r11=1.f-2.f*(xx+zq), r12=2.f*(yz-wx);
    float r20=2.f*(xz-wy),     r21=2.f*(yz+wx),     r22=1.f-2.f*(xx+yy);

    // M = R * diag(s); V = M M^T (symmetric)
    float m00=r00*s0, m01=r01*s1, m02=r02*s2;
    float m10=r10*s0, m11=r11*s1, m12=r12*s2;
    float m20=r20*s0, m21=r21*s1, m22=r22*s2;
    float V00=m00*m00+m01*m01+m02*m02;
    float V01=m00*m10+m01*m11+m02*m12;
    float V02=m00*m20+m01*m21+m02*m22;
    float V11=m10*m10+m11*m11+m12*m12;
    float V12=m10*m20+m11*m21+m12*m22;
    float V22=m20*m20+m21*m21+m22*m22;

    float tanfx = (float)W / (2.f*fx), tanfy = (float)H / (2.f*fy);
    float limx = 1.3f*tanfx, limy = 1.3f*tanfy;
    float txl = fminf(fmaxf(pcx/zs, -limx), limx) * zs;
    float tyl = fminf(fmaxf(pcy/zs, -limy), limy) * zs;
    float iz = 1.f/zs, iz2 = iz*iz;
    float J00 = fx*iz, J02 = -fx*txl*iz2;
    float J11 = fy*iz, J12 = -fy*tyl*iz2;

    // T2 = J @ Rcw (2x3)
    float T00=J00*R00+J02*R20, T01=J00*R01+J02*R21, T02=J00*R02+J02*R22;
    float T10=J11*R10+J12*R20, T11=J11*R11+J12*R21, T12=J11*R12+J12*R22;
    // cov2d = T2 V T2^T + 0.3 I
    float A0=T00*V00+T01*V01+T02*V02;
    float A1=T00*V01+T01*V11+T02*V12;
    float A2=T00*V02+T01*V12+T02*V22;
    float B0=T10*V00+T11*V01+T12*V02;
    float B1=T10*V01+T11*V11+T12*V12;
    float B2=T10*V02+T11*V12+T12*V22;
    float ca = A0*T00+A1*T01+A2*T02 + 0.3f;
    float cb = A0*T10+A1*T11+A2*T12;
    float cc = B0*T10+B1*T11+B2*T12 + 0.3f;

    float det = ca*cc - cb*cb;
    bool valid = (depth > 0.2f) && (det > 0.f);
    float det_s = valid ? det : 1.f;
    float dinv = 1.f/det_s;
    float ci0 =  cc*dinv, ci1 = -cb*dinv, ci2 = ca*dinv;
    float mid = 0.5f*(ca+cc);
    float lam = mid + sqrtf(fmaxf(mid*mid - det, 0.1f));
    float radius = valid ? ceilf(3.f*sqrtf(lam)) : 0.f;
    areas[2*i+0] = radius;
    areas[2*i+1] = radius;

    float alpha = 1.f/(1.f + expf(-alphas_raw[i]));

    // view direction & SH color
    float tw0 = -(R00*t0 + R10*t1 + R20*t2);
    float tw1 = -(R01*t0 + R11*t1 + R21*t2);
    float tw2 = -(R02*t0 + R12*t1 + R22*t2);
    float dx_=pwx-tw0, dy_=pwy-tw1, dz_=pwz-tw2;
    float dn = sqrtf(dx_*dx_+dy_*dy_+dz_*dz_);
    float x=dx_/dn, y=dy_/dn, z=dz_/dn;
    float sxx=x*x, syy=y*y, szz=z*z;
    float sxy=x*y, syz=y*z, sxz=x*z;
    const float* sh = shs + i*48;
    float col[3];
    #pragma unroll
    for (int c = 0; c < 3; ++c) {
        float res = 0.28209479177387814f*sh[0*3+c];
        res += -0.4886025119029199f*y*sh[1*3+c]
             +  0.4886025119029199f*z*sh[2*3+c]
             + -0.4886025119029199f*x*sh[3*3+c];
        res +=  1.0925484305920792f*sxy*sh[4*3+c]
             + -1.0925484305920792f*syz*sh[5*3+c]
             +  0.31539156525252005f*(2.f*szz-sxx-syy)*sh[6*3+c]
             + -1.0925484305920792f*sxz*sh[7*3+c]
             +  0.5462742152960396f*(sxx-syy)*sh[8*3+c];
        res += -0.5900435899266435f*y*(3.f*sxx-syy)*sh[9*3+c]
             +  2.890611442640554f*sxy*z*sh[10*3+c]
             + -0.4570457994644658f*y*(4.f*szz-sxx-syy)*sh[11*3+c]
             +  0.3731763325901154f*z*(2.f*szz-3.f*sxx-3.f*syy)*sh[12*3+c]
             + -0.4570457994644658f*x*(4.f*szz-sxx-syy)*sh[13*3+c]
             +  1.445305721320277f*z*(sxx-syy)*sh[14*3+c]
             + -0.5900435899266435f*x*(sxx-3.f*syy)*sh[15*3+c];
        col[c] = fmaxf(res + 0.5f, 0.f);
    }

    // conservative cull radius^2: alp >= 1/255 requires Q <= 2 log(255 a),
    // and Q >= dist^2 / lam  (lam >= lambda_max(cov2d)); +1px margin.
    float rc2;
    if (!valid || 255.f*alpha < 0.999f) {
        rc2 = -1.f;
    } else {
        float r2 = 2.f*lam*logf(255.f*alpha);
        float r  = sqrtf(fmaxf(r2, 0.f)) + 1.f;
        rc2 = r*r;
    }

    P[0*N+i]=u0;  P[1*N+i]=u1;  P[2*N+i]=ci0; P[3*N+i]=ci1; P[4*N+i]=ci2;
    P[5*N+i]=alpha; P[6*N+i]=col[0]; P[7*N+i]=col[1]; P[8*N+i]=col[2];
    P[9*N+i]=rc2;

    // sortable key: (monotone uint32 of depth) << 32 | index  (stable order)
    unsigned ud = __float_as_uint(depth);
    ud = (ud & 0x80000000u) ? ~ud : (ud | 0x80000000u);
    keys[i] = ((unsigned long long)ud << 32) | (unsigned)i;
}

// ---------------------------------------------------------------------------
// Kernel 2: single-block bitonic sort of (depth,idx) u64 keys in LDS.
// ---------------------------------------------------------------------------
__global__ __launch_bounds__(1024) void k_sort(
    unsigned long long* __restrict__ keys, int N, int n2)
{
    __shared__ unsigned long long s[SORT_MAX];
    for (int i = threadIdx.x; i < n2; i += 1024)
        s[i] = (i < N) ? keys[i] : ~0ull;
    __syncthreads();
    for (int k = 2; k <= n2; k <<= 1) {
        for (int j = k >> 1; j > 0; j >>= 1) {
            for (int i = threadIdx.x; i < n2; i += 1024) {
                int ij = i ^ j;
                if (ij > i) {
                    unsigned long long a = s[i], b = s[ij];
                    bool up = ((i & k) == 0);
                    if ((a > b) == up) { s[i] = b; s[ij] = a; }
                }
            }
            __syncthreads();
        }
    }
    for (int i = threadIdx.x; i < n2; i += 1024)
        if (i < N) keys[i] = s[i];
}

// ---------------------------------------------------------------------------
// Kernel 3: gather params into sorted order.
// Pso: 7 SoA arrays [ci0,ci1,ci2,alpha,r,g,b]; cull: float4(u0,u1,rc2,0).
// ---------------------------------------------------------------------------
__global__ __launch_bounds__(256) void k_gather(
    const unsigned long long* __restrict__ keys,
    const float* __restrict__ Pun, float* __restrict__ Pso,
    float4* __restrict__ cull, int N)
{
    int s = blockIdx.x * 256 + threadIdx.x;
    if (s >= N) return;
    int idx = (int)(unsigned)(keys[s] & 0xffffffffull);
    float u0 = Pun[0*N+idx], u1 = Pun[1*N+idx], rc2 = Pun[9*N+idx];
    cull[s] = make_float4(u0, u1, rc2, 0.f);
    Pso[0*N+s] = Pun[2*N+idx];
    Pso[1*N+s] = Pun[3*N+idx];
    Pso[2*N+s] = Pun[4*N+idx];
    Pso[3*N+s] = Pun[5*N+idx];
    Pso[4*N+s] = Pun[6*N+idx];
    Pso[5*N+s] = Pun[7*N+idx];
    Pso[6*N+s] = Pun[8*N+idx];
}

// ---------------------------------------------------------------------------
// Kernel 4: tiled alpha-compositing render. One 16x16 tile per 256-thread
// block. Per 256-Gaussian chunk: per-thread tile-overlap test, then an
// order-preserving ballot compaction into LDS, then the per-pixel composite
// loop over the compacted (depth-ordered) list. Block-wide early exit when
// all transmittances fall below 1e-4 (exact: w is zeroed there in the ref).
// ---------------------------------------------------------------------------
__global__ __launch_bounds__(256) void k_render(
    const float* __restrict__ P, const float4* __restrict__ cull,
    int N, int W, int H, float* __restrict__ out)
{
    const int tid = threadIdx.x;
    const int tilesX = (W + 15) >> 4;
    const int tX = blockIdx.x % tilesX, tY = blockIdx.x / tilesX;
    const int ix = (tX << 4) + (tid & 15);
    const int iy = (tY << 4) + (tid >> 4);
    const bool inb = (ix < W) && (iy < H);
    const float pxf = (float)ix, pyf = (float)iy;
    const float tx0 = (float)(tX << 4), ty0 = (float)(tY << 4);
    int tx1i = (tX << 4) + 15; if (tx1i > W-1) tx1i = W-1;
    int ty1i = (tY << 4) + 15; if (ty1i > H-1) ty1i = H-1;
    const float tx1 = (float)tx1i, ty1 = (float)ty1i;

    float T = inb ? 1.f : 0.f;
    float aR = 0.f, aG = 0.f, aB = 0.f;

    __shared__ float sU0[256], sU1[256], sC0[256], sC1[256], sC2[256];
    __shared__ float sA[256], sCR[256], sCG[256], sCB[256];
    __shared__ unsigned long long sMask[4];

    const int wave = tid >> 6, lane = tid & 63;

    for (int base = 0; base < N; base += 256) {
        int g = base + tid;
        bool ov = false;
        float u0=0.f,u1=0.f,c0=0.f,c1=0.f,c2=0.f,al=0.f,cr=0.f,cg=0.f,cbl=0.f;
        if (g < N) {
            float4 cu = cull[g];
            u0 = cu.x; u1 = cu.y;
            float cxp = fminf(fmaxf(u0, tx0), tx1);
            float cyp = fminf(fmaxf(u1, ty0), ty1);
            float ddx = u0 - cxp, ddy = u1 - cyp;
            ov = (ddx*ddx + ddy*ddy) <= cu.z;
            if (ov) {
                c0 = P[0*N+g]; c1 = P[1*N+g]; c2 = P[2*N+g]; al = P[3*N+g];
                cr = P[4*N+g]; cg = P[5*N+g]; cbl = P[6*N+g];
            }
        }
        unsigned long long m = __ballot(ov);
        if (lane == 0) sMask[wave] = m;
        __syncthreads();  // masks visible; prev chunk's LDS reads complete
        int cnt = 0, off = 0;
        #pragma unroll
        for (int w2 = 0; w2 < 4; ++w2) {
            int pc = __popcll(sMask[w2]);
            if (w2 < wave) off += pc;
            cnt += pc;
        }
        if (ov) {
            int pos = off + __popcll(m & ((1ull << lane) - 1ull));
            sU0[pos]=u0; sU1[pos]=u1; sC0[pos]=c0; sC1[pos]=c1; sC2[pos]=c2;
            sA[pos]=al; sCR[pos]=cr; sCG[pos]=cg; sCB[pos]=cbl;
        }
        __syncthreads();  // compacted list visible

        for (int e = 0; e < cnt; ++e) {
            float gu0=sU0[e], gu1=sU1[e];
            float gc0=sC0[e], gc1=sC1[e], gc2=sC2[e];
            float ga=sA[e], gr=sCR[e], gg=sCG[e], gb=sCB[e];
            float ddx = pxf - gu0, ddy = pyf - gu1;
            float power = -0.5f*(gc0*ddx*ddx + gc2*ddy*ddy) - gc1*ddx*ddy;
            float alp = fminf(0.99f, ga * __expf(power));
            alp = (power <= 0.f && alp >= (1.0f/255.0f)) ? alp : 0.f;
            float w = (T > 0.0001f) ? alp * T : 0.f;
            aR = fmaf(w, gr, aR);
            aG = fmaf(w, gg, aG);
            aB = fmaf(w, gb, aB);
            T = T - T * alp;
        }
        int done = (T <= 0.0001f) ? 1 : 0;
        if (__syncthreads_and(done)) break;  // also fences LDS for next chunk
    }

    if (inb) {
        int p = iy * W + ix;
        int HWp = W * H;
        out[p] = aR; out[HWp + p] = aG; out[2*HWp + p] = aB;
    }
}

// ---------------------------------------------------------------------------
extern "C" void kernel_launch(void* const* d_in, const int* in_sizes, int n_in,
                              void* d_out, int out_size, void* d_ws, size_t ws_size,
                              hipStream_t stream) {
    const float* pws        = (const float*)d_in[0];
    const float* shs        = (const float*)d_in[1];
    const float* alphas_raw = (const float*)d_in[2];
    const float* scales_raw = (const float*)d_in[3];
    const float* rots_raw   = (const float*)d_in[4];
    // d_in[5] = us (forward value cancels: u + us - us)
    const float* Rcw        = (const float*)d_in[6];
    const float* tcw        = (const float*)d_in[7];
    const float* intr       = (const float*)d_in[8];

    const int N  = in_sizes[0] / 3;
    const int HW = (out_size - 2 * N) / 3;
    int W = 1; while ((long long)W * W < (long long)HW) ++W;  // square image
    const int H = HW / W;

    float* out   = (float*)d_out;
    float* areas = out + 3 * HW;

    int n2 = 1; while (n2 < N) n2 <<= 1;

    // workspace carve-up
    char* ws = (char*)d_ws;
    unsigned long long* keys = (unsigned long long*)ws;          // n2 * 8 B
    float* Pun = (float*)(ws + (size_t)n2 * 8);                  // 10*N floats
    float* Pso = Pun + (size_t)10 * N;                           // 7*N floats
    float4* cullv = (float4*)(Pso + (size_t)7 * N);              // N float4

    int gsN = (N + 255) / 256;
    k_pre<<<gsN, 256, 0, stream>>>(pws, shs, alphas_raw, scales_raw, rots_raw,
                                   Rcw, tcw, intr, N, W, H, areas, keys, Pun);
    k_sort<<<1, 1024, 0, stream>>>(keys, N, n2);
    k_gather<<<gsN, 256, 0, stream>>>(keys, Pun, Pso, cullv, N);
    int tiles = ((W + 15) / 16) * ((H + 15) / 16);
    k_render<<<tiles, 256, 0, stream>>>(Pso, cullv, N, W, H, out);
}

// Round 2
// 130.926 us; speedup vs baseline: 1.8372x; 1.8372x over previous
//
#include <hip/hip_runtime.h>

// ---------------------------------------------------------------------------
// Kernel 1: per-Gaussian preprocessing.
// Computes projection, 2D covariance inverse, radius (areas output), color
// from SH, opacity, conservative cull radius^2, depth sort key, rank=0 init.
// ---------------------------------------------------------------------------
__global__ __launch_bounds__(256) void k_pre(
    const float* __restrict__ pws, const float* __restrict__ shs,
    const float* __restrict__ alphas_raw, const float* __restrict__ scales_raw,
    const float* __restrict__ rots_raw, const float* __restrict__ Rcw,
    const float* __restrict__ tcw, const float* __restrict__ intr,
    int N, int W, int H, float* __restrict__ areas,
    unsigned long long* __restrict__ keys, unsigned* __restrict__ rank,
    float* __restrict__ P)
{
    int i = blockIdx.x * 256 + threadIdx.x;
    if (i >= N) return;
    rank[i] = 0u;  // k_rank (stream-ordered after us) accumulates into this

    float R00=Rcw[0],R01=Rcw[1],R02=Rcw[2];
    float R10=Rcw[3],R11=Rcw[4],R12=Rcw[5];
    float R20=Rcw[6],R21=Rcw[7],R22=Rcw[8];
    float t0=tcw[0],t1=tcw[1],t2=tcw[2];
    float fx=intr[0],fy=intr[1],cx=intr[2],cy=intr[3];

    float pwx=pws[i*3+0], pwy=pws[i*3+1], pwz=pws[i*3+2];
    float pcx = R00*pwx + R01*pwy + R02*pwz + t0;
    float pcy = R10*pwx + R11*pwy + R12*pwz + t1;
    float pcz = R20*pwx + R21*pwy + R22*pwz + t2;
    float depth = pcz;
    float zs = (depth > 0.2f) ? depth : 1.0f;
    float u0 = fx * pcx / zs + cx;
    float u1 = fy * pcy / zs + cy;

    // quaternion -> rotation
    float qw=rots_raw[i*4+0], qx=rots_raw[i*4+1], qy=rots_raw[i*4+2], qz=rots_raw[i*4+3];
    float qn = sqrtf(qw*qw + qx*qx + qy*qy + qz*qz);
    qw/=qn; qx/=qn; qy/=qn; qz/=qn;
    float s0 = expf(scales_raw[i*3+0]);
    float s1 = expf(scales_raw[i*3+1]);
    float s2 = expf(scales_raw[i*3+2]);

    float xx=qx*qx, yy=qy*qy, zq=qz*qz;
    float xy=qx*qy, xz=qx*qz, yz=qy*qz;
    float wx=qw*qx, wy=qw*qy, wz=qw*qz;
    float r00=1.f-2.f*(yy+zq), r01=2.f*(xy-wz),     r02=2.f*(xz+wy);
    float r10=2.f*(xy+wz),     r11=1.f-2.f*(xx+zq), r12=2.f*(yz-wx);
    float r20=2.f*(xz-wy),     r21=2.f*(yz+wx),     r22=1.f-2.f*(xx+yy);

    // M = R * diag(s); V = M M^T (symmetric)
    float m00=r00*s0, m01=r01*s1, m02=r02*s2;
    float m10=r10*s0, m11=r11*s1, m12=r12*s2;
    float m20=r20*s0, m21=r21*s1, m22=r22*s2;
    float V00=m00*m00+m01*m01+m02*m02;
    float V01=m00*m10+m01*m11+m02*m12;
    float V02=m00*m20+m01*m21+m02*m22;
    float V11=m10*m10+m11*m11+m12*m12;
    float V12=m10*m20+m11*m21+m12*m22;
    float V22=m20*m20+m21*m21+m22*m22;

    float tanfx = (float)W / (2.f*fx), tanfy = (float)H / (2.f*fy);
    float limx = 1.3f*tanfx, limy = 1.3f*tanfy;
    float txl = fminf(fmaxf(pcx/zs, -limx), limx) * zs;
    float tyl = fminf(fmaxf(pcy/zs, -limy), limy) * zs;
    float iz = 1.f/zs, iz2 = iz*iz;
    float J00 = fx*iz, J02 = -fx*txl*iz2;
    float J11 = fy*iz, J12 = -fy*tyl*iz2;

    // T2 = J @ Rcw (2x3)
    float T00=J00*R00+J02*R20, T01=J00*R01+J02*R21, T02=J00*R02+J02*R22;
    float T10=J11*R10+J12*R20, T11=J11*R11+J12*R21, T12=J11*R12+J12*R22;
    // cov2d = T2 V T2^T + 0.3 I
    float A0=T00*V00+T01*V01+T02*V02;
    float A1=T00*V01+T01*V11+T02*V12;
    float A2=T00*V02+T01*V12+T02*V22;
    float B0=T10*V00+T11*V01+T12*V02;
    float B1=T10*V01+T11*V11+T12*V12;
    float B2=T10*V02+T11*V12+T12*V22;
    float ca = A0*T00+A1*T01+A2*T02 + 0.3f;
    float cb = A0*T10+A1*T11+A2*T12;
    float cc = B0*T10+B1*T11+B2*T12 + 0.3f;

    float det = ca*cc - cb*cb;
    bool valid = (depth > 0.2f) && (det > 0.f);
    float det_s = valid ? det : 1.f;
    float dinv = 1.f/det_s;
    float ci0 =  cc*dinv, ci1 = -cb*dinv, ci2 = ca*dinv;
    float mid = 0.5f*(ca+cc);
    float lam = mid + sqrtf(fmaxf(mid*mid - det, 0.1f));
    float radius = valid ? ceilf(3.f*sqrtf(lam)) : 0.f;
    areas[2*i+0] = radius;
    areas[2*i+1] = radius;

    float alpha = 1.f/(1.f + expf(-alphas_raw[i]));

    // view direction & SH color
    float tw0 = -(R00*t0 + R10*t1 + R20*t2);
    float tw1 = -(R01*t0 + R11*t1 + R21*t2);
    float tw2 = -(R02*t0 + R12*t1 + R22*t2);
    float dx_=pwx-tw0, dy_=pwy-tw1, dz_=pwz-tw2;
    float dn = sqrtf(dx_*dx_+dy_*dy_+dz_*dz_);
    float x=dx_/dn, y=dy_/dn, z=dz_/dn;
    float sxx=x*x, syy=y*y, szz=z*z;
    float sxy=x*y, syz=y*z, sxz=x*z;
    const float* sh = shs + i*48;
    float col[3];
    #pragma unroll
    for (int c = 0; c < 3; ++c) {
        float res = 0.28209479177387814f*sh[0*3+c];
        res += -0.4886025119029199f*y*sh[1*3+c]
             +  0.4886025119029199f*z*sh[2*3+c]
             + -0.4886025119029199f*x*sh[3*3+c];
        res +=  1.0925484305920792f*sxy*sh[4*3+c]
             + -1.0925484305920792f*syz*sh[5*3+c]
             +  0.31539156525252005f*(2.f*szz-sxx-syy)*sh[6*3+c]
             + -1.0925484305920792f*sxz*sh[7*3+c]
             +  0.5462742152960396f*(sxx-syy)*sh[8*3+c];
        res += -0.5900435899266435f*y*(3.f*sxx-syy)*sh[9*3+c]
             +  2.890611442640554f*sxy*z*sh[10*3+c]
             + -0.4570457994644658f*y*(4.f*szz-sxx-syy)*sh[11*3+c]
             +  0.3731763325901154f*z*(2.f*szz-3.f*sxx-3.f*syy)*sh[12*3+c]
             + -0.4570457994644658f*x*(4.f*szz-sxx-syy)*sh[13*3+c]
             +  1.445305721320277f*z*(sxx-syy)*sh[14*3+c]
             + -0.5900435899266435f*x*(sxx-3.f*syy)*sh[15*3+c];
        col[c] = fmaxf(res + 0.5f, 0.f);
    }

    // conservative cull radius^2: alp >= 1/255 requires Q <= 2 log(255 a),
    // and Q >= dist^2 / lam  (lam >= lambda_max(cov2d)); +1px margin.
    float rc2;
    if (!valid || 255.f*alpha < 0.999f) {
        rc2 = -1.f;
    } else {
        float r2 = 2.f*lam*logf(255.f*alpha);
        float r  = sqrtf(fmaxf(r2, 0.f)) + 1.f;
        rc2 = r*r;
    }

    P[0*N+i]=u0;  P[1*N+i]=u1;  P[2*N+i]=ci0; P[3*N+i]=ci1; P[4*N+i]=ci2;
    P[5*N+i]=alpha; P[6*N+i]=col[0]; P[7*N+i]=col[1]; P[8*N+i]=col[2];
    P[9*N+i]=rc2;

    // sortable key: (monotone uint32 of depth) << 32 | index (unique, stable)
    unsigned ud = __float_as_uint(depth);
    ud = (ud & 0x80000000u) ? ~ud : (ud | 0x80000000u);
    keys[i] = ((unsigned long long)ud << 32) | (unsigned)i;
}

// ---------------------------------------------------------------------------
// Kernel 2: O(N^2) rank sort. Keys are unique, so
//   rank[i] = #{ j : key[j] < key[i] }  == stable argsort position.
// Grid: (i-chunks of 512) x (j-chunks of 512) = 256 blocks at N=8192.
// Each block stages 512 keys in LDS (broadcast reads), each thread ranks
// 2 keys against the chunk, atomicAdd's the partial count.
// ---------------------------------------------------------------------------
#define JC 512
__global__ __launch_bounds__(256) void k_rank(
    const unsigned long long* __restrict__ keys, int N,
    unsigned* __restrict__ rank)
{
    __shared__ unsigned long long sk[JC];
    const int j0 = blockIdx.y * JC;
    for (int t = threadIdx.x; t < JC; t += 256) {
        int j = j0 + t;
        sk[t] = (j < N) ? keys[j] : ~0ull;   // ~0 is > every real key
    }
    __syncthreads();

    const int i0 = blockIdx.x * 512 + threadIdx.x;
    const int i1 = i0 + 256;
    unsigned long long my0 = (i0 < N) ? keys[i0] : 0ull;
    unsigned long long my1 = (i1 < N) ? keys[i1] : 0ull;

    int c0 = 0, c1 = 0;
    const ulonglong2* sk2 = (const ulonglong2*)sk;
    #pragma unroll 4
    for (int t = 0; t < JC/2; ++t) {
        ulonglong2 kk = sk2[t];
        c0 += (kk.x < my0) ? 1 : 0;
        c0 += (kk.y < my0) ? 1 : 0;
        c1 += (kk.x < my1) ? 1 : 0;
        c1 += (kk.y < my1) ? 1 : 0;
    }
    if (i0 < N) atomicAdd(&rank[i0], (unsigned)c0);
    if (i1 < N) atomicAdd(&rank[i1], (unsigned)c1);
}

// ---------------------------------------------------------------------------
// Kernel 3: scatter params into sorted order via rank.
// Pso: 7 SoA arrays [ci0,ci1,ci2,alpha,r,g,b]; cull: float4(u0,u1,rc2,0).
// ---------------------------------------------------------------------------
__global__ __launch_bounds__(256) void k_scatter(
    const unsigned* __restrict__ rank, const float* __restrict__ Pun,
    float* __restrict__ Pso, float4* __restrict__ cull, int N)
{
    int i = blockIdx.x * 256 + threadIdx.x;
    if (i >= N) return;
    int s = (int)rank[i];
    cull[s] = make_float4(Pun[0*N+i], Pun[1*N+i], Pun[9*N+i], 0.f);
    Pso[0*N+s] = Pun[2*N+i];
    Pso[1*N+s] = Pun[3*N+i];
    Pso[2*N+s] = Pun[4*N+i];
    Pso[3*N+s] = Pun[5*N+i];
    Pso[4*N+s] = Pun[6*N+i];
    Pso[5*N+s] = Pun[7*N+i];
    Pso[6*N+s] = Pun[8*N+i];
}

// ---------------------------------------------------------------------------
// Kernel 4: tiled alpha-compositing render. One 16x16 tile per 256-thread
// block. Per 256-Gaussian chunk: per-thread tile-overlap test, then an
// order-preserving ballot compaction into LDS, then the per-pixel composite
// loop over the compacted (depth-ordered) list. Block-wide early exit when
// all transmittances fall below 1e-4 (exact: w is zeroed there in the ref).
// ---------------------------------------------------------------------------
__global__ __launch_bounds__(256) void k_render(
    const float* __restrict__ P, const float4* __restrict__ cull,
    int N, int W, int H, float* __restrict__ out)
{
    const int tid = threadIdx.x;
    const int tilesX = (W + 15) >> 4;
    const int tX = blockIdx.x % tilesX, tY = blockIdx.x / tilesX;
    const int ix = (tX << 4) + (tid & 15);
    const int iy = (tY << 4) + (tid >> 4);
    const bool inb = (ix < W) && (iy < H);
    const float pxf = (float)ix, pyf = (float)iy;
    const float tx0 = (float)(tX << 4), ty0 = (float)(tY << 4);
    int tx1i = (tX << 4) + 15; if (tx1i > W-1) tx1i = W-1;
    int ty1i = (tY << 4) + 15; if (ty1i > H-1) ty1i = H-1;
    const float tx1 = (float)tx1i, ty1 = (float)ty1i;

    float T = inb ? 1.f : 0.f;
    float aR = 0.f, aG = 0.f, aB = 0.f;

    __shared__ float sU0[256], sU1[256], sC0[256], sC1[256], sC2[256];
    __shared__ float sA[256], sCR[256], sCG[256], sCB[256];
    __shared__ unsigned long long sMask[4];

    const int wave = tid >> 6, lane = tid & 63;

    for (int base = 0; base < N; base += 256) {
        int g = base + tid;
        bool ov = false;
        float u0=0.f,u1=0.f,c0=0.f,c1=0.f,c2=0.f,al=0.f,cr=0.f,cg=0.f,cbl=0.f;
        if (g < N) {
            float4 cu = cull[g];
            u0 = cu.x; u1 = cu.y;
            float cxp = fminf(fmaxf(u0, tx0), tx1);
            float cyp = fminf(fmaxf(u1, ty0), ty1);
            float ddx = u0 - cxp, ddy = u1 - cyp;
            ov = (ddx*ddx + ddy*ddy) <= cu.z;
            if (ov) {
                c0 = P[0*N+g]; c1 = P[1*N+g]; c2 = P[2*N+g]; al = P[3*N+g];
                cr = P[4*N+g]; cg = P[5*N+g]; cbl = P[6*N+g];
            }
        }
        unsigned long long m = __ballot(ov);
        if (lane == 0) sMask[wave] = m;
        __syncthreads();  // masks visible; prev chunk's LDS reads complete
        int cnt = 0, off = 0;
        #pragma unroll
        for (int w2 = 0; w2 < 4; ++w2) {
            int pc = __popcll(sMask[w2]);
            if (w2 < wave) off += pc;
            cnt += pc;
        }
        if (ov) {
            int pos = off + __popcll(m & ((1ull << lane) - 1ull));
            sU0[pos]=u0; sU1[pos]=u1; sC0[pos]=c0; sC1[pos]=c1; sC2[pos]=c2;
            sA[pos]=al; sCR[pos]=cr; sCB[pos]=cbl; sCG[pos]=cg;
        }
        __syncthreads();  // compacted list visible

        for (int e = 0; e < cnt; ++e) {
            float gu0=sU0[e], gu1=sU1[e];
            float gc0=sC0[e], gc1=sC1[e], gc2=sC2[e];
            float ga=sA[e], gr=sCR[e], gg=sCG[e], gb=sCB[e];
            float ddx = pxf - gu0, ddy = pyf - gu1;
            float power = -0.5f*(gc0*ddx*ddx + gc2*ddy*ddy) - gc1*ddx*ddy;
            float alp = fminf(0.99f, ga * __expf(power));
            alp = (power <= 0.f && alp >= (1.0f/255.0f)) ? alp : 0.f;
            float w = (T > 0.0001f) ? alp * T : 0.f;
            aR = fmaf(w, gr, aR);
            aG = fmaf(w, gg, aG);
            aB = fmaf(w, gb, aB);
            T = T - T * alp;
        }
        int done = (T <= 0.0001f) ? 1 : 0;
        if (__syncthreads_and(done)) break;  // also fences LDS for next chunk
    }

    if (inb) {
        int p = iy * W + ix;
        int HWp = W * H;
        out[p] = aR; out[HWp + p] = aG; out[2*HWp + p] = aB;
    }
}

// ---------------------------------------------------------------------------
extern "C" void kernel_launch(void* const* d_in, const int* in_sizes, int n_in,
                              void* d_out, int out_size, void* d_ws, size_t ws_size,
                              hipStream_t stream) {
    const float* pws        = (const float*)d_in[0];
    const float* shs        = (const float*)d_in[1];
    const float* alphas_raw = (const float*)d_in[2];
    const float* scales_raw = (const float*)d_in[3];
    const float* rots_raw   = (const float*)d_in[4];
    // d_in[5] = us (forward value cancels: u + us - us)
    const float* Rcw        = (const float*)d_in[6];
    const float* tcw        = (const float*)d_in[7];
    const float* intr       = (const float*)d_in[8];

    const int N  = in_sizes[0] / 3;
    const int HW = (out_size - 2 * N) / 3;
    int W = 1; while ((long long)W * W < (long long)HW) ++W;  // square image
    const int H = HW / W;

    float* out   = (float*)d_out;
    float* areas = out + 3 * HW;

    // workspace carve-up
    char* ws = (char*)d_ws;
    unsigned long long* keys = (unsigned long long*)ws;          // N * 8 B
    unsigned* rank = (unsigned*)(ws + (size_t)N * 8);            // N * 4 B
    float* Pun = (float*)(ws + (size_t)N * 12);                  // 10*N floats
    float* Pso = Pun + (size_t)10 * N;                           // 7*N floats
    float4* cullv = (float4*)(Pso + (size_t)7 * N);              // N float4

    int gsN = (N + 255) / 256;
    k_pre<<<gsN, 256, 0, stream>>>(pws, shs, alphas_raw, scales_raw, rots_raw,
                                   Rcw, tcw, intr, N, W, H, areas, keys, rank, Pun);
    dim3 rgrid((N + 511) / 512, (N + JC - 1) / JC);
    k_rank<<<rgrid, 256, 0, stream>>>(keys, N, rank);
    k_scatter<<<gsN, 256, 0, stream>>>(rank, Pun, Pso, cullv, N);
    int tiles = ((W + 15) / 16) * ((H + 15) / 16);
    k_render<<<tiles, 256, 0, stream>>>(Pso, cullv, N, W, H, out);
}